// Round 2
// baseline (1844.996 us; speedup 1.0000x reference)
//
#include <hip/hip_runtime.h>
#include <hip/hip_bf16.h>
#include <cstddef>

#define DIN 58
#define H1  300
#define H2  100
#define CHUNK 75   // H1 / 4

// ---------------- utility ----------------

__global__ void k_zero(float* __restrict__ p, long n) {
    long i = (long)blockIdx.x * 256 + threadIdx.x;
    long stride = (long)gridDim.x * 256;
    for (; i < n; i += stride) p[i] = 0.f;
}

// ---------------- degree / weights ----------------

__global__ void k_deg(const int* __restrict__ row, float* __restrict__ deg, int E) {
    int e = blockIdx.x * 256 + threadIdx.x;
    if (e < E) atomicAdd(&deg[row[e]], 1.0f);
}

__global__ void k_dinv(float* __restrict__ deg, int n) {
    int i = blockIdx.x * 256 + threadIdx.x;
    if (i < n) {
        float d = deg[i];
        deg[i] = (d > 0.f) ? rsqrtf(fmaxf(d, 1.f)) : 0.f;
    }
}

__global__ void k_w(const int* __restrict__ row, const int* __restrict__ col,
                    const float* __restrict__ dinv, float* __restrict__ w, int E) {
    int e = blockIdx.x * 256 + threadIdx.x;
    if (e < E) w[e] = -dinv[row[e]] * dinv[col[e]];
}

// ---------------- edge gather-scale-scatter: out[dst] += w[e] * X[src] ----------------
// X row stride = F (contiguous chunk buffers).

__global__ __launch_bounds__(256) void k_scatter(const float* __restrict__ X,
                                                 const int* __restrict__ src,
                                                 const int* __restrict__ dst,
                                                 const float* __restrict__ w,
                                                 float* __restrict__ out, int E, int F) {
    int wid  = (blockIdx.x * 256 + threadIdx.x) >> 6;   // one wave per edge
    int lane = threadIdx.x & 63;
    if (wid >= E) return;
    int s = src[wid], d = dst[wid];
    float we = w[wid];
    const float* xr = X + (size_t)s * F;
    float* orow = out + (size_t)d * F;
    for (int f = lane; f < F; f += 64)
        atomicAdd(&orow[f], we * xr[f]);
}

// ---------------- generalized fused GEMM ----------------
// C[row,col](ldc) op= act( A1(lda)@B1(ldb) [+ A2(lda)@B2(ldb)] + bias ) [+ addend(ldc)]
// K2 = 2K if A2 else K.  accum: C += result.  Epilogue order: bias, relu, addend, accum.

#define BM 64
#define BN 64
#define BKK 32

__global__ __launch_bounds__(256) void gemm2(
    const float* __restrict__ A1, const float* __restrict__ A2, int lda,
    const float* __restrict__ B1, const float* __restrict__ B2, int ldb,
    const float* __restrict__ bias, const float* __restrict__ addend,
    float* __restrict__ C, int ldc, int Nrows, int K, int J, int relu, int accum)
{
    __shared__ float As[BKK][BM + 1];   // transposed: As[k][r]
    __shared__ float Bs[BKK][BN + 1];
    const int K2 = A2 ? 2 * K : K;
    const int tid = threadIdx.x;
    const int tx = tid & 15, ty = tid >> 4;
    const int row0 = blockIdx.x * BM;
    const int col0 = blockIdx.y * BN;
    float acc[4][4] = {};

    for (int kt = 0; kt < K2; kt += BKK) {
        #pragma unroll
        for (int q = 0; q < 8; ++q) {               // A tile: 64 rows x 32 k
            int idx = tid + q * 256;
            int r = idx >> 5;
            int kk = idx & 31;
            int kp = kt + kk;
            int row = row0 + r;
            float v = 0.f;
            if (row < Nrows && kp < K2)
                v = (kp < K) ? A1[(size_t)row * lda + kp]
                             : A2[(size_t)row * lda + (kp - K)];
            As[kk][r] = v;
        }
        #pragma unroll
        for (int q = 0; q < 8; ++q) {               // B tile: 32 k x 64 cols
            int idx = tid + q * 256;
            int kk = idx >> 6;
            int c  = idx & 63;
            int kp = kt + kk;
            int col = col0 + c;
            float v = 0.f;
            if (col < J && kp < K2)
                v = (kp < K) ? B1[(size_t)kp * ldb + col]
                             : B2[(size_t)(kp - K) * ldb + col];
            Bs[kk][c] = v;
        }
        __syncthreads();
        int klim = min(BKK, K2 - kt);
        for (int kk = 0; kk < klim; ++kk) {
            float a[4], b[4];
            #pragma unroll
            for (int i = 0; i < 4; ++i) a[i] = As[kk][ty * 4 + i];
            #pragma unroll
            for (int j = 0; j < 4; ++j) b[j] = Bs[kk][tx * 4 + j];
            #pragma unroll
            for (int i = 0; i < 4; ++i)
                #pragma unroll
                for (int j = 0; j < 4; ++j)
                    acc[i][j] += a[i] * b[j];
        }
        __syncthreads();
    }

    for (int i = 0; i < 4; ++i) {
        int row = row0 + ty * 4 + i;
        if (row >= Nrows) continue;
        for (int j = 0; j < 4; ++j) {
            int col = col0 + tx * 4 + j;
            if (col >= J) continue;
            float v = acc[i][j];
            if (bias) v += bias[col];
            if (relu) v = fmaxf(v, 0.f);
            if (addend) v += addend[(size_t)row * ldc + col];
            size_t ci = (size_t)row * ldc + col;
            if (accum) v += C[ci];
            C[ci] = v;
        }
    }
}

// ---------------- elementwise: p = relu(p + bias[col]) ----------------

__global__ void k_bias_relu(float* __restrict__ p, const float* __restrict__ b,
                            int n, int J) {
    int i = blockIdx.x * 256 + threadIdx.x;
    if (i < n) {
        int col = i % J;
        p[i] = fmaxf(p[i] + b[col], 0.f);
    }
}

// ---------------- conv3: out[n] = dot(xs[n], w0) + dot(t3[n], w1) + b ----------------

__global__ __launch_bounds__(256) void k_conv3(const float* __restrict__ xs,
                                               const float* __restrict__ t3,
                                               const float* __restrict__ w0,
                                               const float* __restrict__ w1,
                                               const float* __restrict__ b,
                                               float* __restrict__ out, int n) {
    int wib  = threadIdx.x >> 6;
    int lane = threadIdx.x & 63;
    int nrow = blockIdx.x * 4 + wib;
    if (nrow >= n) return;
    float acc = 0.f;
    for (int f = lane; f < H2; f += 64)
        acc += xs[(size_t)nrow * H2 + f] * w0[f] + t3[(size_t)nrow * H2 + f] * w1[f];
    #pragma unroll
    for (int off = 32; off; off >>= 1) acc += __shfl_down(acc, off);
    if (lane == 0) out[nrow] = acc + b[0];
}

// ---------------- link-logit loss ----------------

__global__ __launch_bounds__(256) void k_loss(const float* __restrict__ z,
                                              const int* __restrict__ ea,
                                              const int* __restrict__ eb,
                                              int E, int mode, float* __restrict__ loss) {
    __shared__ float wsum[4];
    int wid  = threadIdx.x >> 6;
    int lane = threadIdx.x & 63;
    int gw = blockIdx.x * 4 + wid;
    int nw = gridDim.x * 4;
    float sum = 0.f;
    for (int e = gw; e < E; e += nw) {
        int a = ea[e], b = eb[e];
        float d = 0.f;
        for (int f = lane; f < H2; f += 64)
            d += z[(size_t)a * H2 + f] * z[(size_t)b * H2 + f];
        #pragma unroll
        for (int off = 32; off; off >>= 1) d += __shfl_down(d, off);
        if (lane == 0) {
            float s = 1.f / (1.f + expf(-d));
            float t = (mode == 0) ? -logf(s + 1e-15f) : -logf(1.f - s + 1e-15f);
            sum += t;
        }
    }
    if (lane == 0) wsum[wid] = sum;
    __syncthreads();
    if (threadIdx.x == 0)
        atomicAdd(&loss[mode], wsum[0] + wsum[1] + wsum[2] + wsum[3]);
}

__global__ void k_final(const float* __restrict__ loss,
                        const float* __restrict__ c1, const float* __restrict__ c2,
                        float* __restrict__ out, int N, float invEp, float invEn) {
    if (threadIdx.x == 0 && blockIdx.x == 0) {
        out[N]     = loss[0] * invEp + loss[1] * invEn;
        out[N + 1] = c1[0];
        out[N + 2] = c2[0];
    }
}

// ---------------- launch ----------------

extern "C" void kernel_launch(void* const* d_in, const int* in_sizes, int n_in,
                              void* d_out, int out_size, void* d_ws, size_t ws_size,
                              hipStream_t stream) {
    const float* x   = (const float*)d_in[0];
    const int*   ei  = (const int*)d_in[1];
    const int*   nei = (const int*)d_in[2];
    const float* c1w0 = (const float*)d_in[3];
    const float* c1w1 = (const float*)d_in[4];
    const float* c1b  = (const float*)d_in[5];
    const float* c2w0 = (const float*)d_in[6];
    const float* c2w1 = (const float*)d_in[7];
    const float* c2b  = (const float*)d_in[8];
    const float* c3w0 = (const float*)d_in[9];
    const float* c3w1 = (const float*)d_in[10];
    const float* c3b  = (const float*)d_in[11];
    const float* l1w  = (const float*)d_in[12];
    const float* l1b  = (const float*)d_in[13];
    const float* l2w  = (const float*)d_in[14];
    const float* l2b  = (const float*)d_in[15];
    const float* c1s  = (const float*)d_in[16];
    const float* c2s  = (const float*)d_in[17];

    const int N  = in_sizes[0] / DIN;      // 100000
    const int E  = in_sizes[1] / 2;        // 262144
    const int En = in_sizes[2] / 2;        // 262144

    const int* row = ei;        // edge_index[0]
    const int* col = ei + E;    // edge_index[1]

    // ---- workspace layout (peak 146 MB) ----
    char* ws = (char*)d_ws;
    const size_t MB = 1024ull * 1024ull;
    float* wE   = (float*)(ws + 0);                     // E floats (1MB)
    float* deg  = (float*)(ws + 1 * MB);                // N floats (0.4MB)
    float* loss = (float*)(ws + 1 * MB + 512 * 1024);   // 2 floats
    float* t1   = (float*)(ws + 2 * MB);                // N*58  (23.2MB)
    float* x1   = (float*)(ws + 26 * MB);               // N*100 (40MB)
    float* hC   = (float*)(ws + 66 * MB);               // N*75  (30MB) chunk
    float* t2C  = (float*)(ws + 96 * MB);               // N*75  (30MB) chunk
    float* xs   = (float*)(ws + 66 * MB);               // N*100 (40MB) after loop
    float* z    = (float*)(ws + 106 * MB);              // N*100 (40MB) -> peak 146MB
    float* t3   = (float*)(ws + 26 * MB);               // reuse x1 region (40MB)

    const int ZG = 2048;
    int gE = (E + 255) / 256;
    int gScat = (E * 64 + 255) / 256;

    // ---- degrees & edge weights ----
    k_zero<<<ZG, 256, 0, stream>>>(deg, N);
    k_zero<<<1, 256, 0, stream>>>(loss, 2);
    k_deg<<<gE, 256, 0, stream>>>(row, deg, E);
    k_dinv<<<(N + 255) / 256, 256, 0, stream>>>(deg, N);
    k_w<<<gE, 256, 0, stream>>>(row, col, deg, wE, E);

    // ---- conv1 scatter: t1 = segsum(w * x[src] -> dst) ----
    k_zero<<<ZG, 256, 0, stream>>>(t1, (long)N * DIN);
    k_scatter<<<gScat, 256, 0, stream>>>(x, row, col, wE, t1, E, DIN);

    // ---- fused conv1 -> conv2 over 4 column chunks of H1 ----
    k_zero<<<ZG, 256, 0, stream>>>(x1, (long)N * H2);
    dim3 gH((N + BM - 1) / BM, (CHUNK + BN - 1) / BN);      // J=75 -> y=2
    dim3 gX1((N + BM - 1) / BM, (H2 + BN - 1) / BN);        // J=100 -> y=2
    for (int c = 0; c < 4; ++c) {
        int c0 = c * CHUNK;
        // hC = relu(x @ c1w0[:,c0:c0+75] + t1 @ c1w1[:,c0:c0+75] + c1b[c0:])
        gemm2<<<gH, 256, 0, stream>>>(x, t1, DIN,
                                      c1w0 + c0, c1w1 + c0, H1,
                                      c1b + c0, nullptr,
                                      hC, CHUNK, N, DIN, CHUNK, 1, 0);
        // t2C = segsum(w * hC[src] -> dst)
        k_zero<<<ZG, 256, 0, stream>>>(t2C, (long)N * CHUNK);
        k_scatter<<<gScat, 256, 0, stream>>>(hC, row, col, wE, t2C, E, CHUNK);
        // x1 += hC @ c2w0[c0:c0+75,:] + t2C @ c2w1[c0:c0+75,:]
        gemm2<<<gX1, 256, 0, stream>>>(hC, t2C, CHUNK,
                                       c2w0 + (size_t)c0 * H2, c2w1 + (size_t)c0 * H2, H2,
                                       nullptr, nullptr,
                                       x1, H2, N, CHUNK, H2, 0, 1);
    }
    // x1 = relu(x1 + c2b)
    k_bias_relu<<<(N * H2 + 255) / 256, 256, 0, stream>>>(x1, c2b, N * H2, H2);

    // ---- xs = x1 + relu(x@lin1 + b); z = x1 + relu(x@lin2 + b) ----
    gemm2<<<gX1, 256, 0, stream>>>(x, nullptr, DIN, l1w, nullptr, H2,
                                   l1b, x1, xs, H2, N, DIN, H2, 1, 0);
    gemm2<<<gX1, 256, 0, stream>>>(x, nullptr, DIN, l2w, nullptr, H2,
                                   l2b, x1, z, H2, N, DIN, H2, 1, 0);

    // ---- conv3: t3 = segsum(w * xs[src] -> dst); out = xs@w0 + t3@w1 + b ----
    k_zero<<<ZG, 256, 0, stream>>>(t3, (long)N * H2);
    k_scatter<<<gScat, 256, 0, stream>>>(xs, row, col, wE, t3, E, H2);
    k_conv3<<<(N + 3) / 4, 256, 0, stream>>>(xs, t3, c3w0, c3w1, c3b, (float*)d_out, N);

    // ---- losses ----
    k_loss<<<1024, 256, 0, stream>>>(z, ei, ei + E, E, 0, loss);
    k_loss<<<1024, 256, 0, stream>>>(z, nei, nei + En, En, 1, loss);
    k_final<<<1, 64, 0, stream>>>(loss, c1s, c2s, (float*)d_out, N, 1.0f / E, 1.0f / En);
}

// Round 3
// 1561.983 us; speedup vs baseline: 1.1812x; 1.1812x over previous
//
#include <hip/hip_runtime.h>
#include <hip/hip_bf16.h>
#include <cstddef>

#define DIN 58
#define H1  300
#define H2  100
#define RC  25000   // row chunk

// ---------------- utility ----------------

__global__ void k_zero(float* __restrict__ p, long n) {
    long i = (long)blockIdx.x * 256 + threadIdx.x;
    long stride = (long)gridDim.x * 256;
    for (; i < n; i += stride) p[i] = 0.f;
}

// ---------------- degree / weights ----------------

__global__ void k_deg(const int* __restrict__ row, float* __restrict__ deg, int E) {
    int e = blockIdx.x * 256 + threadIdx.x;
    if (e < E) atomicAdd(&deg[row[e]], 1.0f);
}

__global__ void k_dinv(float* __restrict__ deg, int n) {
    int i = blockIdx.x * 256 + threadIdx.x;
    if (i < n) {
        float d = deg[i];
        deg[i] = (d > 0.f) ? rsqrtf(fmaxf(d, 1.f)) : 0.f;
    }
}

__global__ void k_w(const int* __restrict__ row, const int* __restrict__ col,
                    const float* __restrict__ dinv, float* __restrict__ w, int E) {
    int e = blockIdx.x * 256 + threadIdx.x;
    if (e < E) w[e] = -dinv[row[e]] * dinv[col[e]];
}

// ---------------- edge gather-scale-scatter: out[dst] += w[e] * X[src] ----------------

__global__ __launch_bounds__(256) void k_scatter(const float* __restrict__ X,
                                                 const int* __restrict__ src,
                                                 const int* __restrict__ dst,
                                                 const float* __restrict__ w,
                                                 float* __restrict__ out, int E, int F) {
    int wid  = (blockIdx.x * 256 + threadIdx.x) >> 6;   // one wave per edge
    int lane = threadIdx.x & 63;
    if (wid >= E) return;
    int s = src[wid], d = dst[wid];
    float we = w[wid];
    const float* xr = X + (size_t)s * F;
    float* orow = out + (size_t)d * F;
    for (int f = lane; f < F; f += 64)
        atomicAdd(&orow[f], we * xr[f]);
}

// scalar scatter: out[dst[e]] += w[e] * y1[src[e]]
__global__ void k_scatter1(const float* __restrict__ y1, const int* __restrict__ src,
                           const int* __restrict__ dst, const float* __restrict__ w,
                           float* __restrict__ out, int E) {
    int e = blockIdx.x * 256 + threadIdx.x;
    if (e < E) atomicAdd(&out[dst[e]], w[e] * y1[src[e]]);
}

// ---------------- GEMM: C = act(A1@B1 [+A2@B2] + bias) [+ addend] ----------------
// BM=64, BN=128, 256 threads, 4x8 thread tile. K2 = 2K if A2 else K.

__global__ __launch_bounds__(256) void gemmF(
    const float* __restrict__ A1, const float* __restrict__ A2, int lda,
    const float* __restrict__ B1, const float* __restrict__ B2, int ldb,
    const float* __restrict__ bias, const float* __restrict__ addend,
    float* __restrict__ C, int ldc, int Nrows, int K, int J, int relu)
{
    __shared__ float As[32][68];     // [k][row], padded, 16B-aligned rows
    __shared__ float Bs[32][132];    // [k][col], padded, 16B-aligned rows
    const int K2 = A2 ? (K + K) : K;
    const int tid = threadIdx.x;
    const int tx = tid & 15, ty = tid >> 4;
    const int row0 = blockIdx.x * 64;
    const int col0 = blockIdx.y * 128;
    float acc[4][8] = {};

    for (int kt = 0; kt < K2; kt += 32) {
        #pragma unroll
        for (int q = 0; q < 8; ++q) {               // A tile: 64 rows x 32 k
            int idx = tid + q * 256;
            int r = idx >> 5, kk = idx & 31;
            int kp = kt + kk, row = row0 + r;
            float v = 0.f;
            if (row < Nrows && kp < K2)
                v = (kp < K) ? A1[(size_t)row * lda + kp]
                             : A2[(size_t)row * lda + (kp - K)];
            As[kk][r] = v;
        }
        #pragma unroll
        for (int q = 0; q < 16; ++q) {              // B tile: 32 k x 128 cols
            int idx = tid + q * 256;
            int kk = idx >> 7, cc = idx & 127;
            int kp = kt + kk, col = col0 + cc;
            float v = 0.f;
            if (col < J && kp < K2)
                v = (kp < K) ? B1[(size_t)kp * ldb + col]
                             : B2[(size_t)(kp - K) * ldb + col];
            Bs[kk][cc] = v;
        }
        __syncthreads();
        int klim = min(32, K2 - kt);
        for (int kk = 0; kk < klim; ++kk) {
            float4 av = *(const float4*)&As[kk][ty * 4];
            float4 b0 = *(const float4*)&Bs[kk][tx * 4];
            float4 b1 = *(const float4*)&Bs[kk][tx * 4 + 64];
            float a[4] = {av.x, av.y, av.z, av.w};
            float b[8] = {b0.x, b0.y, b0.z, b0.w, b1.x, b1.y, b1.z, b1.w};
            #pragma unroll
            for (int i = 0; i < 4; ++i)
                #pragma unroll
                for (int j = 0; j < 8; ++j)
                    acc[i][j] += a[i] * b[j];
        }
        __syncthreads();
    }

    #pragma unroll
    for (int i = 0; i < 4; ++i) {
        int row = row0 + ty * 4 + i;
        if (row >= Nrows) continue;
        #pragma unroll
        for (int j = 0; j < 8; ++j) {
            int col = col0 + tx * 4 + ((j >> 2) << 6) + (j & 3);
            if (col >= J) continue;
            float v = acc[i][j];
            if (bias) v += bias[col];
            if (relu) v = fmaxf(v, 0.f);
            if (addend) v += addend[(size_t)row * ldc + col];
            C[(size_t)row * ldc + col] = v;
        }
    }
}

// ---------------- elementwise: p = relu(p + bias[col]) ----------------

__global__ void k_bias_relu(float* __restrict__ p, const float* __restrict__ b,
                            int n, int J) {
    int i = blockIdx.x * 256 + threadIdx.x;
    if (i < n) {
        int col = i % J;
        p[i] = fmaxf(p[i] + b[col], 0.f);
    }
}

// ---------------- conv3 dots: out[n] = dot(xs,w0)+b ; y1[n] = dot(xs,w1) ----------------

__global__ __launch_bounds__(256) void k_conv3y(const float* __restrict__ xs,
                                                const float* __restrict__ w0,
                                                const float* __restrict__ w1,
                                                const float* __restrict__ b,
                                                float* __restrict__ out,
                                                float* __restrict__ y1, int n) {
    int wib  = threadIdx.x >> 6;
    int lane = threadIdx.x & 63;
    int nrow = blockIdx.x * 4 + wib;
    if (nrow >= n) return;
    float a0 = 0.f, a1 = 0.f;
    for (int f = lane; f < H2; f += 64) {
        float v = xs[(size_t)nrow * H2 + f];
        a0 += v * w0[f];
        a1 += v * w1[f];
    }
    #pragma unroll
    for (int off = 32; off; off >>= 1) {
        a0 += __shfl_down(a0, off);
        a1 += __shfl_down(a1, off);
    }
    if (lane == 0) {
        out[nrow] = a0 + b[0];
        y1[nrow]  = a1;
    }
}

// ---------------- link-logit loss ----------------

__global__ __launch_bounds__(256) void k_loss(const float* __restrict__ z,
                                              const int* __restrict__ ea,
                                              const int* __restrict__ eb,
                                              int E, int mode, float* __restrict__ loss) {
    __shared__ float wsum[4];
    int wid  = threadIdx.x >> 6;
    int lane = threadIdx.x & 63;
    int gw = blockIdx.x * 4 + wid;
    int nw = gridDim.x * 4;
    float sum = 0.f;
    for (int e = gw; e < E; e += nw) {
        int a = ea[e], b = eb[e];
        float d = 0.f;
        for (int f = lane; f < H2; f += 64)
            d += z[(size_t)a * H2 + f] * z[(size_t)b * H2 + f];
        #pragma unroll
        for (int off = 32; off; off >>= 1) d += __shfl_down(d, off);
        if (lane == 0) {
            float s = 1.f / (1.f + expf(-d));
            float t = (mode == 0) ? -logf(s + 1e-15f) : -logf(1.f - s + 1e-15f);
            sum += t;
        }
    }
    if (lane == 0) wsum[wid] = sum;
    __syncthreads();
    if (threadIdx.x == 0)
        atomicAdd(&loss[mode], wsum[0] + wsum[1] + wsum[2] + wsum[3]);
}

__global__ void k_final(const float* __restrict__ loss,
                        const float* __restrict__ c1, const float* __restrict__ c2,
                        float* __restrict__ out, int N, float invEp, float invEn) {
    if (threadIdx.x == 0 && blockIdx.x == 0) {
        out[N]     = loss[0] * invEp + loss[1] * invEn;
        out[N + 1] = c1[0];
        out[N + 2] = c2[0];
    }
}

// ---------------- launch ----------------

extern "C" void kernel_launch(void* const* d_in, const int* in_sizes, int n_in,
                              void* d_out, int out_size, void* d_ws, size_t ws_size,
                              hipStream_t stream) {
    const float* x   = (const float*)d_in[0];
    const int*   ei  = (const int*)d_in[1];
    const int*   nei = (const int*)d_in[2];
    const float* c1w0 = (const float*)d_in[3];
    const float* c1w1 = (const float*)d_in[4];
    const float* c1b  = (const float*)d_in[5];
    const float* c2w0 = (const float*)d_in[6];
    const float* c2w1 = (const float*)d_in[7];
    const float* c2b  = (const float*)d_in[8];
    const float* c3w0 = (const float*)d_in[9];
    const float* c3w1 = (const float*)d_in[10];
    const float* c3b  = (const float*)d_in[11];
    const float* l1w  = (const float*)d_in[12];
    const float* l1b  = (const float*)d_in[13];
    const float* l2w  = (const float*)d_in[14];
    const float* l2b  = (const float*)d_in[15];
    const float* c1s  = (const float*)d_in[16];
    const float* c2s  = (const float*)d_in[17];

    const int N  = in_sizes[0] / DIN;      // 100000
    const int E  = in_sizes[1] / 2;        // 262144
    const int En = in_sizes[2] / 2;        // 262144

    const int* row = ei;        // src
    const int* col = ei + E;    // dst

    // ---- workspace layout (peak 146 MB) ----
    char* ws = (char*)d_ws;
    const size_t MB = 1024ull * 1024ull;
    float* wE   = (float*)(ws + 0);                     // E (1MB)
    float* deg  = (float*)(ws + 1 * MB);                // N (0.4MB)
    float* loss = (float*)(ws + 1 * MB + 448 * 1024);   // 2
    float* y1   = (float*)(ws + 1 * MB + 512 * 1024);   // N (0.4MB)
    float* t1   = (float*)(ws + 2 * MB);                // N*58 (23.2MB), dead after loop
    float* x1   = (float*)(ws + 26 * MB);               // N*100 (40MB)
    float* hw1  = (float*)(ws + 66 * MB);               // N*100 (40MB), dead after scatter
    float* z    = (float*)(ws + 66 * MB);               // reuse hw1 region
    float* hC   = (float*)(ws + 106 * MB);              // RC*300 (30MB), loop scratch
    float* xs   = (float*)(ws + 106 * MB);              // N*100 (40MB), after loop

    const int ZG = 2048;
    int gE = (E + 255) / 256;
    int gScat = (E * 64 + 255) / 256;

    // ---- degrees & edge weights ----
    k_zero<<<ZG, 256, 0, stream>>>(deg, N);
    k_zero<<<1, 256, 0, stream>>>(loss, 2);
    k_deg<<<gE, 256, 0, stream>>>(row, deg, E);
    k_dinv<<<(N + 255) / 256, 256, 0, stream>>>(deg, N);
    k_w<<<gE, 256, 0, stream>>>(row, col, deg, wE, E);

    // ---- conv1 scatter: t1 = segsum(w * x[src] -> dst), F=58 ----
    k_zero<<<ZG, 256, 0, stream>>>(t1, (long)N * DIN);
    k_scatter<<<gScat, 256, 0, stream>>>(x, row, col, wE, t1, E, DIN);

    // ---- conv1 + conv2 GEMMs per row chunk (no cross-row deps) ----
    for (int c = 0; c < 4; ++c) {
        int r0 = c * RC;
        // hC = relu([x | t1][r0:r0+RC] @ [c1w0; c1w1] + c1b)   (RC x 300)
        dim3 g1((RC + 63) / 64, (H1 + 127) / 128);   // y=3
        gemmF<<<g1, 256, 0, stream>>>(x + (size_t)r0 * DIN, t1 + (size_t)r0 * DIN, DIN,
                                      c1w0, c1w1, H1, c1b, nullptr,
                                      hC, H1, RC, DIN, H1, 1);
        // x1[r0:] = hC @ c2w0 ; hw1[r0:] = hC @ c2w1   (RC x 100 each)
        dim3 g2((RC + 63) / 64, 1);
        gemmF<<<g2, 256, 0, stream>>>(hC, nullptr, H1, c2w0, nullptr, H2,
                                      nullptr, nullptr,
                                      x1 + (size_t)r0 * H2, H2, RC, H1, H2, 0);
        gemmF<<<g2, 256, 0, stream>>>(hC, nullptr, H1, c2w1, nullptr, H2,
                                      nullptr, nullptr,
                                      hw1 + (size_t)r0 * H2, H2, RC, H1, H2, 0);
    }

    // ---- conv2 aggregate: x1[dst] += w*hw1[src]; x1 = relu(x1 + c2b) ----
    k_scatter<<<gScat, 256, 0, stream>>>(hw1, row, col, wE, x1, E, H2);
    k_bias_relu<<<(N * H2 + 255) / 256, 256, 0, stream>>>(x1, c2b, N * H2, H2);

    // ---- xs = x1 + relu(x@lin1 + b); z = x1 + relu(x@lin2 + b) ----
    dim3 gL((N + 63) / 64, 1);
    gemmF<<<gL, 256, 0, stream>>>(x, nullptr, DIN, l1w, nullptr, H2,
                                  l1b, x1, xs, H2, N, DIN, H2, 1);
    gemmF<<<gL, 256, 0, stream>>>(x, nullptr, DIN, l2w, nullptr, H2,
                                  l2b, x1, z, H2, N, DIN, H2, 1);

    // ---- conv3 via linearity: out = xs@w0 + b + scatter(w * (xs@w1)[src]) ----
    k_conv3y<<<(N + 3) / 4, 256, 0, stream>>>(xs, c3w0, c3w1, c3b, (float*)d_out, y1, N);
    k_scatter1<<<gE, 256, 0, stream>>>(y1, row, col, wE, (float*)d_out, E);

    // ---- losses ----
    k_loss<<<1024, 256, 0, stream>>>(z, ei, ei + E, E, 0, loss);
    k_loss<<<1024, 256, 0, stream>>>(z, nei, nei + En, En, 1, loss);
    k_final<<<1, 64, 0, stream>>>(loss, c1s, c2s, (float*)d_out, N, 1.0f / E, 1.0f / En);
}

// Round 4
// 1130.761 us; speedup vs baseline: 1.6316x; 1.3814x over previous
//
#include <hip/hip_runtime.h>
#include <hip/hip_bf16.h>
#include <cstddef>

#define DIN 58
#define H1  300
#define H2  100

// ---------------- utility ----------------

__global__ void k_zero(float* __restrict__ p, long n) {
    long i = (long)blockIdx.x * 256 + threadIdx.x;
    long stride = (long)gridDim.x * 256;
    for (; i < n; i += stride) p[i] = 0.f;
}

// ---------------- degree / weights ----------------

__global__ void k_deg(const int* __restrict__ row, float* __restrict__ deg, int E) {
    int e = blockIdx.x * 256 + threadIdx.x;
    if (e < E) atomicAdd(&deg[row[e]], 1.0f);
}

__global__ void k_dinv(float* __restrict__ deg, int n) {
    int i = blockIdx.x * 256 + threadIdx.x;
    if (i < n) {
        float d = deg[i];
        deg[i] = (d > 0.f) ? rsqrtf(fmaxf(d, 1.f)) : 0.f;
    }
}

__global__ void k_w(const int* __restrict__ row, const int* __restrict__ col,
                    const float* __restrict__ dinv, float* __restrict__ w, int E) {
    int e = blockIdx.x * 256 + threadIdx.x;
    if (e < E) w[e] = -dinv[row[e]] * dinv[col[e]];
}

// ---------------- edge gather-scale-scatter: out[dst] += w[e] * X[src] ----------------

__global__ __launch_bounds__(256) void k_scatter(const float* __restrict__ X,
                                                 const int* __restrict__ src,
                                                 const int* __restrict__ dst,
                                                 const float* __restrict__ w,
                                                 float* __restrict__ out, int E, int F) {
    int wid  = (blockIdx.x * 256 + threadIdx.x) >> 6;   // one wave per edge
    int lane = threadIdx.x & 63;
    if (wid >= E) return;
    int s = src[wid], d = dst[wid];
    float we = w[wid];
    const float* xr = X + (size_t)s * F;
    float* orow = out + (size_t)d * F;
    for (int f = lane; f < F; f += 64)
        atomicAdd(&orow[f], we * xr[f]);
}

// scalar scatter: out[dst[e]] += w[e] * y1[src[e]]
__global__ void k_scatter1(const float* __restrict__ y1, const int* __restrict__ src,
                           const int* __restrict__ dst, const float* __restrict__ w,
                           float* __restrict__ out, int E) {
    int e = blockIdx.x * 256 + threadIdx.x;
    if (e < E) atomicAdd(&out[dst[e]], w[e] * y1[src[e]]);
}

// ---------------- GEMM (conv1): C = relu([A1|A2]@[B1;B2] + bias) ----------------
// BM=64, BN=128, 256 threads, 4x8 tile. K2 = 2K if A2 else K.

__global__ __launch_bounds__(256) void gemmF(
    const float* __restrict__ A1, const float* __restrict__ A2, int lda,
    const float* __restrict__ B1, const float* __restrict__ B2, int ldb,
    const float* __restrict__ bias,
    float* __restrict__ C, int ldc, int Nrows, int K, int J, int relu)
{
    __shared__ float As[32][68];
    __shared__ float Bs[32][132];
    const int K2 = A2 ? (K + K) : K;
    const int tid = threadIdx.x;
    const int tx = tid & 15, ty = tid >> 4;
    const int row0 = blockIdx.x * 64;
    const int col0 = blockIdx.y * 128;
    float acc[4][8] = {};

    for (int kt = 0; kt < K2; kt += 32) {
        #pragma unroll
        for (int q = 0; q < 8; ++q) {
            int idx = tid + q * 256;
            int r = idx >> 5, kk = idx & 31;
            int kp = kt + kk, row = row0 + r;
            float v = 0.f;
            if (row < Nrows && kp < K2)
                v = (kp < K) ? A1[(size_t)row * lda + kp]
                             : A2[(size_t)row * lda + (kp - K)];
            As[kk][r] = v;
        }
        #pragma unroll
        for (int q = 0; q < 16; ++q) {
            int idx = tid + q * 256;
            int kk = idx >> 7, cc = idx & 127;
            int kp = kt + kk, col = col0 + cc;
            float v = 0.f;
            if (col < J && kp < K2)
                v = (kp < K) ? B1[(size_t)kp * ldb + col]
                             : B2[(size_t)(kp - K) * ldb + col];
            Bs[kk][cc] = v;
        }
        __syncthreads();
        int klim = min(32, K2 - kt);
        for (int kk = 0; kk < klim; ++kk) {
            float4 av = *(const float4*)&As[kk][ty * 4];
            float4 b0 = *(const float4*)&Bs[kk][tx * 4];
            float4 b1 = *(const float4*)&Bs[kk][tx * 4 + 64];
            float a[4] = {av.x, av.y, av.z, av.w};
            float b[8] = {b0.x, b0.y, b0.z, b0.w, b1.x, b1.y, b1.z, b1.w};
            #pragma unroll
            for (int i = 0; i < 4; ++i)
                #pragma unroll
                for (int j = 0; j < 8; ++j)
                    acc[i][j] += a[i] * b[j];
        }
        __syncthreads();
    }

    #pragma unroll
    for (int i = 0; i < 4; ++i) {
        int row = row0 + ty * 4 + i;
        if (row >= Nrows) continue;
        #pragma unroll
        for (int j = 0; j < 8; ++j) {
            int col = col0 + tx * 4 + ((j >> 2) << 6) + (j & 3);
            if (col >= J) continue;
            float v = acc[i][j];
            if (bias) v += bias[col];
            if (relu) v = fmaxf(v, 0.f);
            C[(size_t)row * ldc + col] = v;
        }
    }
}

// ---------------- dual-output GEMM: {Ca,Cb} = relu?(A@{Ba,Bb} + bias?) + addend? ----
// Column-concat: virtual J2=2J cols; col<J -> (Ba,biasA,Ca), else (Bb,biasB,Cb).

__global__ __launch_bounds__(256) void gemmPair(
    const float* __restrict__ A, int lda,
    const float* __restrict__ Ba, const float* __restrict__ Bb, int ldb,
    const float* __restrict__ biasA, const float* __restrict__ biasB,
    const float* __restrict__ addend,
    float* __restrict__ Ca, float* __restrict__ Cb, int ldc,
    int Nrows, int K, int J, int relu)
{
    __shared__ float As[32][68];
    __shared__ float Bs[32][132];
    const int tid = threadIdx.x;
    const int tx = tid & 15, ty = tid >> 4;
    const int row0 = blockIdx.x * 64;
    const int col0 = blockIdx.y * 128;
    const int J2 = 2 * J;
    float acc[4][8] = {};

    for (int kt = 0; kt < K; kt += 32) {
        #pragma unroll
        for (int q = 0; q < 8; ++q) {
            int idx = tid + q * 256;
            int r = idx >> 5, kk = idx & 31;
            int kp = kt + kk, row = row0 + r;
            float v = 0.f;
            if (row < Nrows && kp < K)
                v = A[(size_t)row * lda + kp];
            As[kk][r] = v;
        }
        #pragma unroll
        for (int q = 0; q < 16; ++q) {
            int idx = tid + q * 256;
            int kk = idx >> 7, cc = idx & 127;
            int kp = kt + kk, col = col0 + cc;
            float v = 0.f;
            if (kp < K && col < J2)
                v = (col < J) ? Ba[(size_t)kp * ldb + col]
                              : Bb[(size_t)kp * ldb + (col - J)];
            Bs[kk][cc] = v;
        }
        __syncthreads();
        int klim = min(32, K - kt);
        for (int kk = 0; kk < klim; ++kk) {
            float4 av = *(const float4*)&As[kk][ty * 4];
            float4 b0 = *(const float4*)&Bs[kk][tx * 4];
            float4 b1 = *(const float4*)&Bs[kk][tx * 4 + 64];
            float a[4] = {av.x, av.y, av.z, av.w};
            float b[8] = {b0.x, b0.y, b0.z, b0.w, b1.x, b1.y, b1.z, b1.w};
            #pragma unroll
            for (int i = 0; i < 4; ++i)
                #pragma unroll
                for (int j = 0; j < 8; ++j)
                    acc[i][j] += a[i] * b[j];
        }
        __syncthreads();
    }

    #pragma unroll
    for (int i = 0; i < 4; ++i) {
        int row = row0 + ty * 4 + i;
        if (row >= Nrows) continue;
        #pragma unroll
        for (int j = 0; j < 8; ++j) {
            int col = col0 + tx * 4 + ((j >> 2) << 6) + (j & 3);
            if (col >= J2) continue;
            int isA = col < J;
            int mcol = isA ? col : col - J;
            float v = acc[i][j];
            const float* bias = isA ? biasA : biasB;
            if (bias) v += bias[mcol];
            if (relu) v = fmaxf(v, 0.f);
            if (addend) v += addend[(size_t)row * H2 + mcol];
            float* C = isA ? Ca : Cb;
            C[(size_t)row * ldc + mcol] = v;
        }
    }
}

// ---------------- elementwise: p = relu(p + bias[col]) ----------------

__global__ void k_bias_relu(float* __restrict__ p, const float* __restrict__ b,
                            int n, int J) {
    int i = blockIdx.x * 256 + threadIdx.x;
    if (i < n) {
        int col = i % J;
        p[i] = fmaxf(p[i] + b[col], 0.f);
    }
}

// ---------------- conv3 dots: out[n] = dot(xs,w0)+b ; y1[n] = dot(xs,w1) ----------------

__global__ __launch_bounds__(256) void k_conv3y(const float* __restrict__ xs,
                                                const float* __restrict__ w0,
                                                const float* __restrict__ w1,
                                                const float* __restrict__ b,
                                                float* __restrict__ out,
                                                float* __restrict__ y1, int n) {
    int wib  = threadIdx.x >> 6;
    int lane = threadIdx.x & 63;
    int nrow = blockIdx.x * 4 + wib;
    if (nrow >= n) return;
    float a0 = 0.f, a1 = 0.f;
    for (int f = lane; f < H2; f += 64) {
        float v = xs[(size_t)nrow * H2 + f];
        a0 += v * w0[f];
        a1 += v * w1[f];
    }
    #pragma unroll
    for (int off = 32; off; off >>= 1) {
        a0 += __shfl_down(a0, off);
        a1 += __shfl_down(a1, off);
    }
    if (lane == 0) {
        out[nrow] = a0 + b[0];
        y1[nrow]  = a1;
    }
}

// ---------------- link-logit loss ----------------

__global__ __launch_bounds__(256) void k_loss(const float* __restrict__ z,
                                              const int* __restrict__ ea,
                                              const int* __restrict__ eb,
                                              int E, int mode, float* __restrict__ loss) {
    __shared__ float wsum[4];
    int wid  = threadIdx.x >> 6;
    int lane = threadIdx.x & 63;
    int gw = blockIdx.x * 4 + wid;
    int nw = gridDim.x * 4;
    float sum = 0.f;
    for (int e = gw; e < E; e += nw) {
        int a = ea[e], b = eb[e];
        float d = 0.f;
        for (int f = lane; f < H2; f += 64)
            d += z[(size_t)a * H2 + f] * z[(size_t)b * H2 + f];
        #pragma unroll
        for (int off = 32; off; off >>= 1) d += __shfl_down(d, off);
        if (lane == 0) {
            float s = 1.f / (1.f + expf(-d));
            float t = (mode == 0) ? -logf(s + 1e-15f) : -logf(1.f - s + 1e-15f);
            sum += t;
        }
    }
    if (lane == 0) wsum[wid] = sum;
    __syncthreads();
    if (threadIdx.x == 0)
        atomicAdd(&loss[mode], wsum[0] + wsum[1] + wsum[2] + wsum[3]);
}

__global__ void k_final(const float* __restrict__ loss,
                        const float* __restrict__ c1, const float* __restrict__ c2,
                        float* __restrict__ out, int N, float invEp, float invEn) {
    if (threadIdx.x == 0 && blockIdx.x == 0) {
        out[N]     = loss[0] * invEp + loss[1] * invEn;
        out[N + 1] = c1[0];
        out[N + 2] = c2[0];
    }
}

// ---------------- launch ----------------

extern "C" void kernel_launch(void* const* d_in, const int* in_sizes, int n_in,
                              void* d_out, int out_size, void* d_ws, size_t ws_size,
                              hipStream_t stream) {
    const float* x   = (const float*)d_in[0];
    const int*   ei  = (const int*)d_in[1];
    const int*   nei = (const int*)d_in[2];
    const float* c1w0 = (const float*)d_in[3];
    const float* c1w1 = (const float*)d_in[4];
    const float* c1b  = (const float*)d_in[5];
    const float* c2w0 = (const float*)d_in[6];
    const float* c2w1 = (const float*)d_in[7];
    const float* c2b  = (const float*)d_in[8];
    const float* c3w0 = (const float*)d_in[9];
    const float* c3w1 = (const float*)d_in[10];
    const float* c3b  = (const float*)d_in[11];
    const float* l1w  = (const float*)d_in[12];
    const float* l1b  = (const float*)d_in[13];
    const float* l2w  = (const float*)d_in[14];
    const float* l2b  = (const float*)d_in[15];
    const float* c1s  = (const float*)d_in[16];
    const float* c2s  = (const float*)d_in[17];

    const int N  = in_sizes[0] / DIN;      // 100000
    const int E  = in_sizes[1] / 2;        // 262144
    const int En = in_sizes[2] / 2;        // 262144

    const int* row = ei;        // src
    const int* col = ei + E;    // dst

    // ---- workspace layout ----
    char* ws = (char*)d_ws;
    const size_t MB = 1024ull * 1024ull;
    float* wE   = (float*)(ws + 0);                     // E (1MB)
    float* deg  = (float*)(ws + 1 * MB);                // N (0.4MB)
    float* loss = (float*)(ws + 1 * MB + 448 * 1024);   // 2
    float* y1   = (float*)(ws + 1 * MB + 512 * 1024);   // N (0.4MB)
    float* t1   = (float*)(ws + 2 * MB);                // N*58 (23.2MB), dead after conv1
    float* x1   = (float*)(ws + 26 * MB);               // N*100 (40MB)
    float* hw1  = (float*)(ws + 66 * MB);               // N*100 (40MB), dead after scatter
    float* z    = (float*)(ws + 66 * MB);               // reuse hw1 region
    float* hC   = (float*)(ws + 106 * MB);              // adaptive: up to N*300 (120MB)
    float* xs   = (float*)(ws + 106 * MB);              // N*100 (40MB), after conv2

    // adaptive chunk size for hC from actual workspace size (deterministic)
    size_t hOff = 106 * MB;
    size_t availB = (ws_size > hOff + MB) ? (ws_size - hOff - MB) : 0;
    long maxRows = (long)(availB / ((size_t)H1 * 4));
    if (maxRows < 16384) maxRows = 16384;   // floor (ws >= 146MB verified working)
    if (maxRows > N) maxRows = N;

    const int ZG = 2048;
    int gE = (E + 255) / 256;
    int gScat = (E * 64 + 255) / 256;

    // ---- degrees & edge weights ----
    k_zero<<<ZG, 256, 0, stream>>>(deg, N);
    k_zero<<<1, 256, 0, stream>>>(loss, 2);
    k_deg<<<gE, 256, 0, stream>>>(row, deg, E);
    k_dinv<<<(N + 255) / 256, 256, 0, stream>>>(deg, N);
    k_w<<<gE, 256, 0, stream>>>(row, col, deg, wE, E);

    // ---- conv1 scatter: t1 = segsum(w * x[src] -> dst), F=58 ----
    k_zero<<<ZG, 256, 0, stream>>>(t1, (long)N * DIN);
    k_scatter<<<gScat, 256, 0, stream>>>(x, row, col, wE, t1, E, DIN);

    // ---- conv1 GEMM + conv2 dual GEMM per row chunk ----
    for (long r0 = 0; r0 < N; r0 += maxRows) {
        long rc = (N - r0 < maxRows) ? (N - r0) : maxRows;
        dim3 g1((rc + 63) / 64, (H1 + 127) / 128);          // y=3
        gemmF<<<g1, 256, 0, stream>>>(x + (size_t)r0 * DIN, t1 + (size_t)r0 * DIN, DIN,
                                      c1w0, c1w1, H1, c1b,
                                      hC, H1, (int)rc, DIN, H1, 1);
        dim3 g2((rc + 63) / 64, 2);                          // J2=200
        gemmPair<<<g2, 256, 0, stream>>>(hC, H1, c2w0, c2w1, H2,
                                         nullptr, nullptr, nullptr,
                                         x1 + (size_t)r0 * H2, hw1 + (size_t)r0 * H2, H2,
                                         (int)rc, H1, H2, 0);
    }

    // ---- conv2 aggregate: x1[dst] += w*hw1[src]; x1 = relu(x1 + c2b) ----
    k_scatter<<<gScat, 256, 0, stream>>>(hw1, row, col, wE, x1, E, H2);
    k_bias_relu<<<(N * H2 + 255) / 256, 256, 0, stream>>>(x1, c2b, N * H2, H2);

    // ---- xs = x1 + relu(x@lin1+b1); z = x1 + relu(x@lin2+b2) — one dispatch ----
    dim3 gL((N + 63) / 64, 2);
    gemmPair<<<gL, 256, 0, stream>>>(x, DIN, l1w, l2w, H2, l1b, l2b, x1,
                                     xs, z, H2, N, DIN, H2, 1);

    // ---- conv3 via linearity: out = xs@w0 + b + scatter(w * (xs@w1)[src]) ----
    k_conv3y<<<(N + 3) / 4, 256, 0, stream>>>(xs, c3w0, c3w1, c3b, (float*)d_out, y1, N);
    k_scatter1<<<gE, 256, 0, stream>>>(y1, row, col, wE, (float*)d_out, E);

    // ---- losses ----
    k_loss<<<1024, 256, 0, stream>>>(z, ei, ei + E, E, 0, loss);
    k_loss<<<1024, 256, 0, stream>>>(z, nei, nei + En, En, 1, loss);
    k_final<<<1, 64, 0, stream>>>(loss, c1s, c2s, (float*)d_out, N, 1.0f / E, 1.0f / En);
}

// Round 5
// 712.671 us; speedup vs baseline: 2.5888x; 1.5867x over previous
//
#include <hip/hip_runtime.h>
#include <hip/hip_bf16.h>
#include <cstddef>

#define DIN 58
#define H1  300
#define H2  100

using bf16x8 = __attribute__((ext_vector_type(8))) short;
using f32x4  = __attribute__((ext_vector_type(4))) float;

__device__ inline unsigned short f2bf(float f) {
    union { float f; unsigned int u; } v; v.f = f;
    unsigned int r = v.u + 0x7fff + ((v.u >> 16) & 1);   // RNE
    return (unsigned short)(r >> 16);
}
__device__ inline float bf2f(unsigned short h) {
    union { unsigned int u; float f; } v; v.u = ((unsigned int)h) << 16;
    return v.f;
}

// ---------------- utility ----------------

__global__ void k_zero(float* __restrict__ p, long n) {
    long i = (long)blockIdx.x * 256 + threadIdx.x;
    long stride = (long)gridDim.x * 256;
    for (; i < n; i += stride) p[i] = 0.f;
}

// ---------------- degree / weights ----------------

__global__ void k_deg(const int* __restrict__ row, float* __restrict__ deg, int E) {
    int e = blockIdx.x * 256 + threadIdx.x;
    if (e < E) atomicAdd(&deg[row[e]], 1.0f);
}

__global__ void k_dinv(float* __restrict__ deg, int n) {
    int i = blockIdx.x * 256 + threadIdx.x;
    if (i < n) {
        float d = deg[i];
        deg[i] = (d > 0.f) ? rsqrtf(fmaxf(d, 1.f)) : 0.f;
    }
}

__global__ void k_w(const int* __restrict__ row, const int* __restrict__ col,
                    const float* __restrict__ dinv, float* __restrict__ w, int E) {
    int e = blockIdx.x * 256 + threadIdx.x;
    if (e < E) w[e] = -dinv[row[e]] * dinv[col[e]];
}

// ---------------- edge scatters ----------------

__global__ __launch_bounds__(256) void k_scatter(const float* __restrict__ X,
                                                 const int* __restrict__ src,
                                                 const int* __restrict__ dst,
                                                 const float* __restrict__ w,
                                                 float* __restrict__ out, int E, int F) {
    int wid  = (blockIdx.x * 256 + threadIdx.x) >> 6;
    int lane = threadIdx.x & 63;
    if (wid >= E) return;
    int s = src[wid], d = dst[wid];
    float we = w[wid];
    const float* xr = X + (size_t)s * F;
    float* orow = out + (size_t)d * F;
    for (int f = lane; f < F; f += 64)
        atomicAdd(&orow[f], we * xr[f]);
}

__global__ __launch_bounds__(256) void k_scatter_bf(const unsigned short* __restrict__ X,
                                                    const int* __restrict__ src,
                                                    const int* __restrict__ dst,
                                                    const float* __restrict__ w,
                                                    float* __restrict__ out, int E, int F) {
    int wid  = (blockIdx.x * 256 + threadIdx.x) >> 6;
    int lane = threadIdx.x & 63;
    if (wid >= E) return;
    int s = src[wid], d = dst[wid];
    float we = w[wid];
    const unsigned short* xr = X + (size_t)s * F;
    float* orow = out + (size_t)d * F;
    for (int f = lane; f < F; f += 64)
        atomicAdd(&orow[f], we * bf2f(xr[f]));
}

__global__ void k_scatter1(const float* __restrict__ y1, const int* __restrict__ src,
                           const int* __restrict__ dst, const float* __restrict__ w,
                           float* __restrict__ out, int E) {
    int e = blockIdx.x * 256 + threadIdx.x;
    if (e < E) atomicAdd(&out[dst[e]], w[e] * y1[src[e]]);
}

// ---------------- conversions ----------------

// Abf[n][128] = bf16([x[n][0:58] | t1[n][0:58] | zeros])
__global__ void k_cvtA(const float* __restrict__ x, const float* __restrict__ t1,
                       unsigned short* __restrict__ Abf, int N) {
    int i = blockIdx.x * 256 + threadIdx.x;
    if (i >= N * 128) return;
    int nrow = i >> 7, k = i & 127;
    float v = 0.f;
    if (k < DIN) v = x[(size_t)nrow * DIN + k];
    else if (k < 2 * DIN) v = t1[(size_t)nrow * DIN + (k - DIN)];
    Abf[i] = f2bf(v);
}

// Bt[j][k] (j in [0,J), k in [0,Kpad)): k<K -> B1[k][j]; K<=k<2K -> B2[k-K][j]; else 0
__global__ void k_cvtB(const float* __restrict__ B1, const float* __restrict__ B2,
                       unsigned short* __restrict__ Bt, int K, int J, int Kpad) {
    int i = blockIdx.x * 256 + threadIdx.x;
    if (i >= J * Kpad) return;
    int j = i / Kpad, k = i % Kpad;
    float v = 0.f;
    if (k < K) v = B1[(size_t)k * J + j];
    else if (B2 && k < 2 * K) v = B2[(size_t)(k - K) * J + j];
    Bt[i] = f2bf(v);
}

// column-concat pair: Bt[(2J)][Kpad]: j<J -> Ba[k][j], else Bb[k][j-J]; k<K else 0
__global__ void k_cvtBpair(const float* __restrict__ Ba, const float* __restrict__ Bb,
                           unsigned short* __restrict__ Bt, int K, int J, int Kpad) {
    int i = blockIdx.x * 256 + threadIdx.x;
    if (i >= 2 * J * Kpad) return;
    int j = i / Kpad, k = i % Kpad;
    float v = 0.f;
    if (k < K) v = (j < J) ? Ba[(size_t)k * J + j] : Bb[(size_t)k * J + (j - J)];
    Bt[i] = f2bf(v);
}

// ---------------- bf16 MFMA GEMM: 128x128 tile, 4 waves, 16x16x32 ----------------
// A: [M][lda] bf16 row-major. Bt: [Jtot][ldb] bf16 (col-major: row index = output col).
// mode 0: Cbf[row][ldcb] = bf16(relu(acc + bias[col])), col<Jtot; zeros for Jtot<=col<ldcb.
// mode 1: col<H2 -> Ca[row*H2+col] = acc ; H2<=col<Jtot -> Cbf[row*H2+col-H2] = bf16(acc).

__global__ __launch_bounds__(256) void gemm_mfma(
    const unsigned short* __restrict__ A, int lda,
    const unsigned short* __restrict__ Bt, int ldb,
    const float* __restrict__ bias, int relu, int mode,
    float* __restrict__ Ca, unsigned short* __restrict__ Cbf,
    int M, int Ksteps, int Jtot, int ldcb)
{
    __shared__ unsigned short As[128][40];
    __shared__ unsigned short Bs[128][40];
    const int tid = threadIdx.x;
    const int wave = tid >> 6, lane = tid & 63;
    const int wr = wave >> 1, wc = wave & 1;
    const int row0 = blockIdx.x * 128;
    const int col0 = blockIdx.y * 128;
    const int tr = tid >> 1;            // 0..127
    const int tk = (tid & 1) * 16;      // 0 / 16

    f32x4 acc[4][4] = {};

    for (int ks = 0; ks < Ksteps; ++ks) {
        int kt = ks * 32;
        {   // stage A tile: row row0+tr, k kt+tk..+15
            int grow = row0 + tr;
            bf16x8 v0 = {}, v1 = {};
            if (grow < M) {
                const unsigned short* p = A + (size_t)grow * lda + kt + tk;
                v0 = *(const bf16x8*)p;
                v1 = *(const bf16x8*)(p + 8);
            }
            *(bf16x8*)&As[tr][tk]     = v0;
            *(bf16x8*)&As[tr][tk + 8] = v1;
        }
        {   // stage B tile: out-col col0+tr, k kt+tk..+15
            int gcol = col0 + tr;
            bf16x8 v0 = {}, v1 = {};
            if (gcol < Jtot) {
                const unsigned short* p = Bt + (size_t)gcol * ldb + kt + tk;
                v0 = *(const bf16x8*)p;
                v1 = *(const bf16x8*)(p + 8);
            }
            *(bf16x8*)&Bs[tr][tk]     = v0;
            *(bf16x8*)&Bs[tr][tk + 8] = v1;
        }
        __syncthreads();

        const int kofs = (lane >> 4) * 8;
        bf16x8 af[4], bg[4];
        const int arow = wr * 64 + (lane & 15);
        const int bcol = wc * 64 + (lane & 15);
        #pragma unroll
        for (int m = 0; m < 4; ++m) af[m] = *(const bf16x8*)&As[arow + m * 16][kofs];
        #pragma unroll
        for (int n = 0; n < 4; ++n) bg[n] = *(const bf16x8*)&Bs[bcol + n * 16][kofs];
        #pragma unroll
        for (int m = 0; m < 4; ++m)
            #pragma unroll
            for (int n = 0; n < 4; ++n)
                acc[m][n] = __builtin_amdgcn_mfma_f32_16x16x32_bf16(af[m], bg[n], acc[m][n], 0, 0, 0);
        __syncthreads();
    }

    // epilogue: C/D frag -> col = lane&15, row = (lane>>4)*4 + i
    #pragma unroll
    for (int m = 0; m < 4; ++m) {
        #pragma unroll
        for (int n = 0; n < 4; ++n) {
            int col = col0 + wc * 64 + n * 16 + (lane & 15);
            #pragma unroll
            for (int i = 0; i < 4; ++i) {
                int row = row0 + wr * 64 + m * 16 + (lane >> 4) * 4 + i;
                if (row >= M) continue;
                float v = acc[m][n][i];
                if (mode == 0) {
                    if (col < ldcb) {
                        float ov = 0.f;
                        if (col < Jtot) {
                            ov = v + bias[col];
                            if (relu) ov = fmaxf(ov, 0.f);
                        }
                        Cbf[(size_t)row * ldcb + col] = f2bf(ov);
                    }
                } else {
                    if (col < Jtot) {
                        if (col < H2) Ca[(size_t)row * H2 + col] = v;
                        else          Cbf[(size_t)row * H2 + (col - H2)] = f2bf(v);
                    }
                }
            }
        }
    }
}

// ---------------- dual-output fp32 GEMM (lin1+lin2) ----------------

__global__ __launch_bounds__(256) void gemmPair(
    const float* __restrict__ A, int lda,
    const float* __restrict__ Ba, const float* __restrict__ Bb, int ldb,
    const float* __restrict__ biasA, const float* __restrict__ biasB,
    const float* __restrict__ addend,
    float* __restrict__ Ca, float* __restrict__ Cb, int ldc,
    int Nrows, int K, int J, int relu)
{
    __shared__ float As[32][68];
    __shared__ float Bs[32][132];
    const int tid = threadIdx.x;
    const int tx = tid & 15, ty = tid >> 4;
    const int row0 = blockIdx.x * 64;
    const int col0 = blockIdx.y * 128;
    const int J2 = 2 * J;
    float acc[4][8] = {};

    for (int kt = 0; kt < K; kt += 32) {
        #pragma unroll
        for (int q = 0; q < 8; ++q) {
            int idx = tid + q * 256;
            int r = idx >> 5, kk = idx & 31;
            int kp = kt + kk, row = row0 + r;
            float v = 0.f;
            if (row < Nrows && kp < K) v = A[(size_t)row * lda + kp];
            As[kk][r] = v;
        }
        #pragma unroll
        for (int q = 0; q < 16; ++q) {
            int idx = tid + q * 256;
            int kk = idx >> 7, cc = idx & 127;
            int kp = kt + kk, col = col0 + cc;
            float v = 0.f;
            if (kp < K && col < J2)
                v = (col < J) ? Ba[(size_t)kp * ldb + col]
                              : Bb[(size_t)kp * ldb + (col - J)];
            Bs[kk][cc] = v;
        }
        __syncthreads();
        int klim = min(32, K - kt);
        for (int kk = 0; kk < klim; ++kk) {
            float4 av = *(const float4*)&As[kk][ty * 4];
            float4 b0 = *(const float4*)&Bs[kk][tx * 4];
            float4 b1 = *(const float4*)&Bs[kk][tx * 4 + 64];
            float a[4] = {av.x, av.y, av.z, av.w};
            float b[8] = {b0.x, b0.y, b0.z, b0.w, b1.x, b1.y, b1.z, b1.w};
            #pragma unroll
            for (int i = 0; i < 4; ++i)
                #pragma unroll
                for (int j = 0; j < 8; ++j)
                    acc[i][j] += a[i] * b[j];
        }
        __syncthreads();
    }

    #pragma unroll
    for (int i = 0; i < 4; ++i) {
        int row = row0 + ty * 4 + i;
        if (row >= Nrows) continue;
        #pragma unroll
        for (int j = 0; j < 8; ++j) {
            int col = col0 + tx * 4 + ((j >> 2) << 6) + (j & 3);
            if (col >= J2) continue;
            int isA = col < J;
            int mcol = isA ? col : col - J;
            float v = acc[i][j];
            const float* bias = isA ? biasA : biasB;
            if (bias) v += bias[mcol];
            if (relu) v = fmaxf(v, 0.f);
            if (addend) v += addend[(size_t)row * H2 + mcol];
            float* C = isA ? Ca : Cb;
            C[(size_t)row * ldc + mcol] = v;
        }
    }
}

// ---------------- elementwise: p = relu(p + bias[col]) ----------------

__global__ void k_bias_relu(float* __restrict__ p, const float* __restrict__ b,
                            int n, int J) {
    int i = blockIdx.x * 256 + threadIdx.x;
    if (i < n) {
        int col = i % J;
        p[i] = fmaxf(p[i] + b[col], 0.f);
    }
}

// ---------------- conv3 dots ----------------

__global__ __launch_bounds__(256) void k_conv3y(const float* __restrict__ xs,
                                                const float* __restrict__ w0,
                                                const float* __restrict__ w1,
                                                const float* __restrict__ b,
                                                float* __restrict__ out,
                                                float* __restrict__ y1, int n) {
    int wib  = threadIdx.x >> 6;
    int lane = threadIdx.x & 63;
    int nrow = blockIdx.x * 4 + wib;
    if (nrow >= n) return;
    float a0 = 0.f, a1 = 0.f;
    for (int f = lane; f < H2; f += 64) {
        float v = xs[(size_t)nrow * H2 + f];
        a0 += v * w0[f];
        a1 += v * w1[f];
    }
    #pragma unroll
    for (int off = 32; off; off >>= 1) {
        a0 += __shfl_down(a0, off);
        a1 += __shfl_down(a1, off);
    }
    if (lane == 0) {
        out[nrow] = a0 + b[0];
        y1[nrow]  = a1;
    }
}

// ---------------- link-logit loss ----------------

__global__ __launch_bounds__(256) void k_loss(const float* __restrict__ z,
                                              const int* __restrict__ ea,
                                              const int* __restrict__ eb,
                                              int E, int mode, float* __restrict__ loss) {
    __shared__ float wsum[4];
    int wid  = threadIdx.x >> 6;
    int lane = threadIdx.x & 63;
    int gw = blockIdx.x * 4 + wid;
    int nw = gridDim.x * 4;
    float sum = 0.f;
    for (int e = gw; e < E; e += nw) {
        int a = ea[e], b = eb[e];
        float d = 0.f;
        for (int f = lane; f < H2; f += 64)
            d += z[(size_t)a * H2 + f] * z[(size_t)b * H2 + f];
        #pragma unroll
        for (int off = 32; off; off >>= 1) d += __shfl_down(d, off);
        if (lane == 0) {
            float s = 1.f / (1.f + expf(-d));
            float t = (mode == 0) ? -logf(s + 1e-15f) : -logf(1.f - s + 1e-15f);
            sum += t;
        }
    }
    if (lane == 0) wsum[wid] = sum;
    __syncthreads();
    if (threadIdx.x == 0)
        atomicAdd(&loss[mode], wsum[0] + wsum[1] + wsum[2] + wsum[3]);
}

__global__ void k_final(const float* __restrict__ loss,
                        const float* __restrict__ c1, const float* __restrict__ c2,
                        float* __restrict__ out, int N, float invEp, float invEn) {
    if (threadIdx.x == 0 && blockIdx.x == 0) {
        out[N]     = loss[0] * invEp + loss[1] * invEn;
        out[N + 1] = c1[0];
        out[N + 2] = c2[0];
    }
}

// ---------------- launch ----------------

extern "C" void kernel_launch(void* const* d_in, const int* in_sizes, int n_in,
                              void* d_out, int out_size, void* d_ws, size_t ws_size,
                              hipStream_t stream) {
    const float* x   = (const float*)d_in[0];
    const int*   ei  = (const int*)d_in[1];
    const int*   nei = (const int*)d_in[2];
    const float* c1w0 = (const float*)d_in[3];
    const float* c1w1 = (const float*)d_in[4];
    const float* c1b  = (const float*)d_in[5];
    const float* c2w0 = (const float*)d_in[6];
    const float* c2w1 = (const float*)d_in[7];
    const float* c2b  = (const float*)d_in[8];
    const float* c3w0 = (const float*)d_in[9];
    const float* c3w1 = (const float*)d_in[10];
    const float* c3b  = (const float*)d_in[11];
    const float* l1w  = (const float*)d_in[12];
    const float* l1b  = (const float*)d_in[13];
    const float* l2w  = (const float*)d_in[14];
    const float* l2b  = (const float*)d_in[15];
    const float* c1s  = (const float*)d_in[16];
    const float* c2s  = (const float*)d_in[17];

    const int N  = in_sizes[0] / DIN;      // 100000
    const int E  = in_sizes[1] / 2;        // 262144
    const int En = in_sizes[2] / 2;        // 262144

    const int* row = ei;        // src
    const int* col = ei + E;    // dst

    // ---- workspace layout (peak 127 MB) ----
    char* ws = (char*)d_ws;
    const size_t MB = 1024ull * 1024ull;
    float* wE    = (float*)(ws + 0);                    // 1MB
    float* deg   = (float*)(ws + 1 * MB);               // 0.4MB
    float* y1    = (float*)(ws + 1 * MB + 512 * 1024);  // 0.4MB
    float* loss  = (float*)(ws + 1 * MB + 960 * 1024);  // 8B
    unsigned short* Bt1 = (unsigned short*)(ws + 2 * MB);          // 300*128*2 = 75KB
    unsigned short* Bt2 = (unsigned short*)(ws + 2 * MB + 256*1024); // 200*320*2 = 125KB
    float* x1    = (float*)(ws + 3 * MB);               // N*100 (40MB)   [conv2 -> lin]
    unsigned short* Abf = (unsigned short*)(ws + 3 * MB); // N*128*2 (25.6MB) [cvtA -> conv1]
    float* t1    = (float*)(ws + 30 * MB);              // N*58 (23.2MB)  [scatter -> cvtA]
    unsigned short* hC  = (unsigned short*)(ws + 43 * MB); // N*320*2 (64MB) [conv1 -> conv2]
    float* xs    = (float*)(ws + 43 * MB);              // N*100 (40MB)   [lin -> conv3]
    float* z     = (float*)(ws + 83 * MB);              // N*100 (40MB)   [lin -> loss]
    unsigned short* hw1b = (unsigned short*)(ws + 107 * MB); // N*100*2 (20MB) [conv2 -> scatter]

    const int ZG = 2048;
    int gE = (E + 255) / 256;
    int gScat = (E * 64 + 255) / 256;

    // ---- degrees & edge weights ----
    k_zero<<<ZG, 256, 0, stream>>>(deg, N);
    k_zero<<<1, 256, 0, stream>>>(loss, 2);
    k_deg<<<gE, 256, 0, stream>>>(row, deg, E);
    k_dinv<<<(N + 255) / 256, 256, 0, stream>>>(deg, N);
    k_w<<<gE, 256, 0, stream>>>(row, col, deg, wE, E);

    // ---- weight conversions (tiny) ----
    k_cvtB<<<(300 * 128 + 255) / 256, 256, 0, stream>>>(c1w0, c1w1, Bt1, DIN, H1, 128);
    k_cvtBpair<<<(200 * 320 + 255) / 256, 256, 0, stream>>>(c2w0, c2w1, Bt2, H1, H2, 320);

    // ---- conv1 scatter: t1 = segsum(w * x[src] -> dst), F=58 ----
    k_zero<<<ZG, 256, 0, stream>>>(t1, (long)N * DIN);
    k_scatter<<<gScat, 256, 0, stream>>>(x, row, col, wE, t1, E, DIN);

    // ---- pack A = [x | t1] -> bf16 [N][128] ----
    k_cvtA<<<(N * 128 + 255) / 256, 256, 0, stream>>>(x, t1, Abf, N);

    // ---- conv1 MFMA: hC[N][320]bf16 = relu(Abf @ Bt1 + c1b), pad cols zeroed ----
    {
        dim3 g((N + 127) / 128, 3);   // cols 0..383, stores col<320
        gemm_mfma<<<g, 256, 0, stream>>>(Abf, 128, Bt1, 128, c1b, 1, 0,
                                         nullptr, hC, N, 4, H1, 320);
    }

    // ---- conv2 MFMA: x1 = hC @ c2w0 (fp32) ; hw1b = hC @ c2w1 (bf16) ----
    {
        dim3 g((N + 127) / 128, 2);   // cols 0..255, stores col<200
        gemm_mfma<<<g, 256, 0, stream>>>(hC, 320, Bt2, 320, nullptr, 0, 1,
                                         x1, hw1b, N, 10, 200, 0);
    }

    // ---- conv2 aggregate: x1[dst] += w*hw1[src]; x1 = relu(x1 + c2b) ----
    k_scatter_bf<<<gScat, 256, 0, stream>>>(hw1b, row, col, wE, x1, E, H2);
    k_bias_relu<<<(N * H2 + 255) / 256, 256, 0, stream>>>(x1, c2b, N * H2, H2);

    // ---- xs = x1 + relu(x@lin1+b1); z = x1 + relu(x@lin2+b2) ----
    dim3 gL((N + 63) / 64, 2);
    gemmPair<<<gL, 256, 0, stream>>>(x, DIN, l1w, l2w, H2, l1b, l2b, x1,
                                     xs, z, H2, N, DIN, H2, 1);

    // ---- conv3: out = xs@w0 + b + scatter(w * (xs@w1)[src]) ----
    k_conv3y<<<(N + 3) / 4, 256, 0, stream>>>(xs, c3w0, c3w1, c3b, (float*)d_out, y1, N);
    k_scatter1<<<gE, 256, 0, stream>>>(y1, row, col, wE, (float*)d_out, E);

    // ---- losses ----
    k_loss<<<1024, 256, 0, stream>>>(z, ei, ei + E, E, 0, loss);
    k_loss<<<1024, 256, 0, stream>>>(z, nei, nei + En, En, 1, loss);
    k_final<<<1, 64, 0, stream>>>(loss, c1s, c2s, (float*)d_out, N, 1.0f / E, 1.0f / En);
}

// Round 6
// 547.923 us; speedup vs baseline: 3.3673x; 1.3007x over previous
//
#include <hip/hip_runtime.h>
#include <hip/hip_bf16.h>
#include <cstddef>

#define DIN 58
#define H1  300
#define H2  100

using bf16x8 = __attribute__((ext_vector_type(8))) short;
using f32x4  = __attribute__((ext_vector_type(4))) float;

__device__ inline unsigned short f2bf(float f) {
    union { float f; unsigned int u; } v; v.f = f;
    unsigned int r = v.u + 0x7fff + ((v.u >> 16) & 1);   // RNE
    return (unsigned short)(r >> 16);
}
__device__ inline float bf2f(unsigned short h) {
    union { unsigned int u; float f; } v; v.u = ((unsigned int)h) << 16;
    return v.f;
}

// ---------------- utility ----------------

__global__ void k_zero(float* __restrict__ p, long n) {
    long i = (long)blockIdx.x * 256 + threadIdx.x;
    long stride = (long)gridDim.x * 256;
    for (; i < n; i += stride) p[i] = 0.f;
}

// ---------------- degree / weights / CSR ----------------

__global__ void k_hist(const int* __restrict__ dst, int* __restrict__ cnt, int E) {
    int e = blockIdx.x * 256 + threadIdx.x;
    if (e < E) atomicAdd(&cnt[dst[e]], 1);
}

__global__ void k_dinvI(const int* __restrict__ cnt, float* __restrict__ dinv, int n) {
    int i = blockIdx.x * 256 + threadIdx.x;
    if (i < n) {
        int c = cnt[i];
        dinv[i] = (c > 0) ? rsqrtf((float)c) : 0.f;
    }
}

__global__ void k_w(const int* __restrict__ row, const int* __restrict__ col,
                    const float* __restrict__ dinv, float* __restrict__ w, int E) {
    int e = blockIdx.x * 256 + threadIdx.x;
    if (e < E) w[e] = -dinv[row[e]] * dinv[col[e]];
}

// block scan: 1024 items/block (256 thr x 4)
__global__ __launch_bounds__(256) void k_scan1(const int* __restrict__ cnt,
                                               int* __restrict__ offs,
                                               int* __restrict__ bsum, int N) {
    __shared__ int ts[256];
    int b = blockIdx.x, t = threadIdx.x;
    int base = b * 1024 + t * 4;
    int v0 = (base + 0 < N) ? cnt[base + 0] : 0;
    int v1 = (base + 1 < N) ? cnt[base + 1] : 0;
    int v2 = (base + 2 < N) ? cnt[base + 2] : 0;
    int v3 = (base + 3 < N) ? cnt[base + 3] : 0;
    ts[t] = v0 + v1 + v2 + v3;
    __syncthreads();
    for (int off = 1; off < 256; off <<= 1) {
        int u = (t >= off) ? ts[t - off] : 0;
        __syncthreads();
        ts[t] += u;
        __syncthreads();
    }
    int ex = (t > 0) ? ts[t - 1] : 0;
    if (base + 0 < N) offs[base + 0] = ex;
    if (base + 1 < N) offs[base + 1] = ex + v0;
    if (base + 2 < N) offs[base + 2] = ex + v0 + v1;
    if (base + 3 < N) offs[base + 3] = ex + v0 + v1 + v2;
    if (t == 255) bsum[b] = ts[255];
}

__global__ __launch_bounds__(256) void k_scan2(int* __restrict__ bsum, int nb) {
    __shared__ int ts[256];
    int t = threadIdx.x;
    ts[t] = (t < nb) ? bsum[t] : 0;
    __syncthreads();
    for (int off = 1; off < 256; off <<= 1) {
        int u = (t >= off) ? ts[t - off] : 0;
        __syncthreads();
        ts[t] += u;
        __syncthreads();
    }
    if (t < nb) bsum[t] = (t > 0) ? ts[t - 1] : 0;
}

__global__ void k_scan3(int* __restrict__ offs, const int* __restrict__ bsum, int N) {
    int i = blockIdx.x * 256 + threadIdx.x;
    if (i < N) offs[i] += bsum[i >> 10];
}

__global__ void k_reorder(const int* __restrict__ row, const int* __restrict__ col,
                          const float* __restrict__ wE, const int* __restrict__ offs,
                          int* __restrict__ cur, int* __restrict__ srcS,
                          float* __restrict__ wS, int E) {
    int e = blockIdx.x * 256 + threadIdx.x;
    if (e < E) {
        int d = col[e];
        int p = offs[d] + atomicAdd(&cur[d], 1);
        srcS[p] = row[e];
        wS[p] = wE[e];
    }
}

// ---------------- CSR segmented reductions ----------------

// per node: t1 = sum w*x[src]; Abf[node] = [bf16(x) | 0 x6 | bf16(t1) | 0 x6]
__global__ __launch_bounds__(256) void k_agg1(const float* __restrict__ x,
                                              const int* __restrict__ srcS,
                                              const float* __restrict__ wS,
                                              const int* __restrict__ offs,
                                              const int* __restrict__ cnt,
                                              unsigned short* __restrict__ Abf, int N) {
    int node = blockIdx.x * 4 + (threadIdx.x >> 6);
    int lane = threadIdx.x & 63;
    if (node >= N) return;
    int b0 = offs[node], b1 = b0 + cnt[node];
    float acc = 0.f;
    for (int i = b0; i < b1; ++i) {
        int s = srcS[i];
        float w = wS[i];
        if (lane < DIN) acc += w * x[(size_t)s * DIN + lane];
    }
    float xv = (lane < DIN) ? x[(size_t)node * DIN + lane] : 0.f;
    Abf[(size_t)node * 128 + lane]      = (lane < DIN) ? f2bf(xv)  : 0;
    Abf[(size_t)node * 128 + 64 + lane] = (lane < DIN) ? f2bf(acc) : 0;
}

// per node: x1[node] = relu(x1[node] + sum w*hw1b[src] + c2b)
__global__ __launch_bounds__(256) void k_agg2(const unsigned short* __restrict__ hw1b,
                                              const int* __restrict__ srcS,
                                              const float* __restrict__ wS,
                                              const int* __restrict__ offs,
                                              const int* __restrict__ cnt,
                                              const float* __restrict__ c2b,
                                              float* __restrict__ x1, int N) {
    int node = blockIdx.x * 4 + (threadIdx.x >> 6);
    int lane = threadIdx.x & 63;
    if (node >= N) return;
    int b0 = offs[node], b1 = b0 + cnt[node];
    float a0 = 0.f, a1 = 0.f;
    for (int i = b0; i < b1; ++i) {
        int s = srcS[i];
        float w = wS[i];
        const unsigned short* hr = hw1b + (size_t)s * H2;
        a0 += w * bf2f(hr[lane]);
        if (lane < H2 - 64) a1 += w * bf2f(hr[lane + 64]);
    }
    size_t base = (size_t)node * H2;
    x1[base + lane] = fmaxf(x1[base + lane] + a0 + c2b[lane], 0.f);
    if (lane < H2 - 64)
        x1[base + 64 + lane] = fmaxf(x1[base + 64 + lane] + a1 + c2b[64 + lane], 0.f);
}

// per node: out[node] += sum w*y1[src]
__global__ void k_agg3(const float* __restrict__ y1, const int* __restrict__ srcS,
                       const float* __restrict__ wS, const int* __restrict__ offs,
                       const int* __restrict__ cnt, float* __restrict__ out, int N) {
    int node = blockIdx.x * 256 + threadIdx.x;
    if (node >= N) return;
    int b0 = offs[node], b1 = b0 + cnt[node];
    float a = 0.f;
    for (int i = b0; i < b1; ++i) a += wS[i] * y1[srcS[i]];
    out[node] += a;
}

// ---------------- weight packs ----------------

__global__ void k_packB1(const float* __restrict__ w0, const float* __restrict__ w1,
                         unsigned short* __restrict__ Bt) {
    int i = blockIdx.x * 256 + threadIdx.x;    // 300*128
    if (i >= H1 * 128) return;
    int j = i >> 7, k = i & 127;
    float v = 0.f;
    if (k < DIN) v = w0[(size_t)k * H1 + j];
    else if (k >= 64 && k < 64 + DIN) v = w1[(size_t)(k - 64) * H1 + j];
    Bt[i] = f2bf(v);
}

__global__ void k_packB2(const float* __restrict__ w0, const float* __restrict__ w1,
                         unsigned short* __restrict__ Bt) {
    int i = blockIdx.x * 256 + threadIdx.x;    // 200*320
    if (i >= 200 * 320) return;
    int j = i / 320, k = i % 320;
    float v = 0.f;
    if (k < H1) v = (j < H2) ? w0[(size_t)k * H2 + j] : w1[(size_t)k * H2 + (j - H2)];
    Bt[i] = f2bf(v);
}

__global__ void k_packBL(const float* __restrict__ w1, const float* __restrict__ w2,
                         unsigned short* __restrict__ Bt) {
    int i = blockIdx.x * 256 + threadIdx.x;    // 256*64
    if (i >= 256 * 64) return;
    int j = i >> 6, k = i & 63;
    float v = 0.f;
    if (k < DIN) {
        if (j < H2) v = w1[(size_t)k * H2 + j];
        else if (j >= 128 && j < 128 + H2) v = w2[(size_t)k * H2 + (j - 128)];
    }
    Bt[i] = f2bf(v);
}

// ---------------- bf16 MFMA GEMM: 128x128 tile, 4 waves, 16x16x32 ----------------
// mode 0: Cbf[row][ldcb] = bf16(relu(acc + bias[col])) for col<Jtot, 0 pad to ldcb.
// mode 1: col<H2 -> Ca[row*H2+col] = acc ; H2<=col<Jtot -> Cbf[row*H2+col-H2] = bf16(acc).

__global__ __launch_bounds__(256) void gemm_mfma(
    const unsigned short* __restrict__ A, int lda,
    const unsigned short* __restrict__ Bt, int ldb,
    const float* __restrict__ bias, int relu, int mode,
    float* __restrict__ Ca, unsigned short* __restrict__ Cbf,
    int M, int Ksteps, int Jtot, int ldcb)
{
    __shared__ unsigned short As[128][40];
    __shared__ unsigned short Bs[128][40];
    const int tid = threadIdx.x;
    const int wave = tid >> 6, lane = tid & 63;
    const int wr = wave >> 1, wc = wave & 1;
    const int row0 = blockIdx.x * 128;
    const int col0 = blockIdx.y * 128;
    const int tr = tid >> 1;
    const int tk = (tid & 1) * 16;

    f32x4 acc[4][4] = {};

    for (int ks = 0; ks < Ksteps; ++ks) {
        int kt = ks * 32;
        {
            int grow = row0 + tr;
            bf16x8 v0 = {}, v1 = {};
            if (grow < M) {
                const unsigned short* p = A + (size_t)grow * lda + kt + tk;
                v0 = *(const bf16x8*)p;
                v1 = *(const bf16x8*)(p + 8);
            }
            *(bf16x8*)&As[tr][tk]     = v0;
            *(bf16x8*)&As[tr][tk + 8] = v1;
        }
        {
            int gcol = col0 + tr;
            bf16x8 v0 = {}, v1 = {};
            if (gcol < Jtot) {
                const unsigned short* p = Bt + (size_t)gcol * ldb + kt + tk;
                v0 = *(const bf16x8*)p;
                v1 = *(const bf16x8*)(p + 8);
            }
            *(bf16x8*)&Bs[tr][tk]     = v0;
            *(bf16x8*)&Bs[tr][tk + 8] = v1;
        }
        __syncthreads();

        const int kofs = (lane >> 4) * 8;
        bf16x8 af[4], bg[4];
        const int arow = wr * 64 + (lane & 15);
        const int bcol = wc * 64 + (lane & 15);
        #pragma unroll
        for (int m = 0; m < 4; ++m) af[m] = *(const bf16x8*)&As[arow + m * 16][kofs];
        #pragma unroll
        for (int n = 0; n < 4; ++n) bg[n] = *(const bf16x8*)&Bs[bcol + n * 16][kofs];
        #pragma unroll
        for (int m = 0; m < 4; ++m)
            #pragma unroll
            for (int n = 0; n < 4; ++n)
                acc[m][n] = __builtin_amdgcn_mfma_f32_16x16x32_bf16(af[m], bg[n], acc[m][n], 0, 0, 0);
        __syncthreads();
    }

    #pragma unroll
    for (int m = 0; m < 4; ++m) {
        #pragma unroll
        for (int n = 0; n < 4; ++n) {
            int col = col0 + wc * 64 + n * 16 + (lane & 15);
            #pragma unroll
            for (int i = 0; i < 4; ++i) {
                int row = row0 + wr * 64 + m * 16 + (lane >> 4) * 4 + i;
                if (row >= M) continue;
                float v = acc[m][n][i];
                if (mode == 0) {
                    if (col < ldcb) {
                        float ov = 0.f;
                        if (col < Jtot) {
                            ov = v + bias[col];
                            if (relu) ov = fmaxf(ov, 0.f);
                        }
                        Cbf[(size_t)row * ldcb + col] = f2bf(ov);
                    }
                } else {
                    if (col < Jtot) {
                        if (col < H2) Ca[(size_t)row * H2 + col] = v;
                        else          Cbf[(size_t)row * H2 + (col - H2)] = f2bf(v);
                    }
                }
            }
        }
    }
}

// ---------------- lin1+lin2 MFMA: xs/z = x1 + relu(x @ w + b), bf16 out ----------------
// A = Abf (lda=128, K=64: x-part). Bt [256][64]: j<100 -> l1w, 128<=j<228 -> l2w.

__global__ __launch_bounds__(256) void k_linpair(
    const unsigned short* __restrict__ A,
    const unsigned short* __restrict__ Bt,
    const float* __restrict__ l1b, const float* __restrict__ l2b,
    const float* __restrict__ x1,
    unsigned short* __restrict__ xsb, unsigned short* __restrict__ zb, int M)
{
    __shared__ unsigned short As[128][40];
    __shared__ unsigned short Bs[128][40];
    const int tid = threadIdx.x;
    const int wave = tid >> 6, lane = tid & 63;
    const int wr = wave >> 1, wc = wave & 1;
    const int row0 = blockIdx.x * 128;
    const int col0 = blockIdx.y * 128;
    const int tr = tid >> 1;
    const int tk = (tid & 1) * 16;

    f32x4 acc[4][4] = {};

    for (int ks = 0; ks < 2; ++ks) {
        int kt = ks * 32;
        {
            int grow = row0 + tr;
            bf16x8 v0 = {}, v1 = {};
            if (grow < M) {
                const unsigned short* p = A + (size_t)grow * 128 + kt + tk;
                v0 = *(const bf16x8*)p;
                v1 = *(const bf16x8*)(p + 8);
            }
            *(bf16x8*)&As[tr][tk]     = v0;
            *(bf16x8*)&As[tr][tk + 8] = v1;
        }
        {
            int gcol = col0 + tr;
            bf16x8 v0 = {}, v1 = {};
            const unsigned short* p = Bt + (size_t)gcol * 64 + kt + tk;
            v0 = *(const bf16x8*)p;
            v1 = *(const bf16x8*)(p + 8);
            *(bf16x8*)&Bs[tr][tk]     = v0;
            *(bf16x8*)&Bs[tr][tk + 8] = v1;
        }
        __syncthreads();

        const int kofs = (lane >> 4) * 8;
        bf16x8 af[4], bg[4];
        const int arow = wr * 64 + (lane & 15);
        const int bcol = wc * 64 + (lane & 15);
        #pragma unroll
        for (int m = 0; m < 4; ++m) af[m] = *(const bf16x8*)&As[arow + m * 16][kofs];
        #pragma unroll
        for (int n = 0; n < 4; ++n) bg[n] = *(const bf16x8*)&Bs[bcol + n * 16][kofs];
        #pragma unroll
        for (int m = 0; m < 4; ++m)
            #pragma unroll
            for (int n = 0; n < 4; ++n)
                acc[m][n] = __builtin_amdgcn_mfma_f32_16x16x32_bf16(af[m], bg[n], acc[m][n], 0, 0, 0);
        __syncthreads();
    }

    #pragma unroll
    for (int m = 0; m < 4; ++m) {
        #pragma unroll
        for (int n = 0; n < 4; ++n) {
            int jv = col0 + wc * 64 + n * 16 + (lane & 15);
            #pragma unroll
            for (int i = 0; i < 4; ++i) {
                int row = row0 + wr * 64 + m * 16 + (lane >> 4) * 4 + i;
                if (row >= M) continue;
                float v = acc[m][n][i];
                if (jv < 128) {
                    int c = jv;
                    if (c < H2) {
                        float o = x1[(size_t)row * H2 + c] + fmaxf(v + l1b[c], 0.f);
                        xsb[(size_t)row * H2 + c] = f2bf(o);
                    }
                } else {
                    int c = jv - 128;
                    if (c < H2) {
                        float o = x1[(size_t)row * H2 + c] + fmaxf(v + l2b[c], 0.f);
                        zb[(size_t)row * H2 + c] = f2bf(o);
                    }
                }
            }
        }
    }
}

// ---------------- conv3 dots (bf16 xs) ----------------

__global__ __launch_bounds__(256) void k_conv3y(const unsigned short* __restrict__ xs,
                                                const float* __restrict__ w0,
                                                const float* __restrict__ w1,
                                                const float* __restrict__ b,
                                                float* __restrict__ out,
                                                float* __restrict__ y1, int n) {
    int wib  = threadIdx.x >> 6;
    int lane = threadIdx.x & 63;
    int nrow = blockIdx.x * 4 + wib;
    if (nrow >= n) return;
    float a0 = 0.f, a1 = 0.f;
    for (int f = lane; f < H2; f += 64) {
        float v = bf2f(xs[(size_t)nrow * H2 + f]);
        a0 += v * w0[f];
        a1 += v * w1[f];
    }
    #pragma unroll
    for (int off = 32; off; off >>= 1) {
        a0 += __shfl_down(a0, off);
        a1 += __shfl_down(a1, off);
    }
    if (lane == 0) {
        out[nrow] = a0 + b[0];
        y1[nrow]  = a1;
    }
}

// ---------------- link-logit loss (bf16 z) ----------------

__global__ __launch_bounds__(256) void k_loss(const unsigned short* __restrict__ z,
                                              const int* __restrict__ ea,
                                              const int* __restrict__ eb,
                                              int E, int mode, float* __restrict__ loss) {
    __shared__ float wsum[4];
    int wid  = threadIdx.x >> 6;
    int lane = threadIdx.x & 63;
    int gw = blockIdx.x * 4 + wid;
    int nw = gridDim.x * 4;
    float sum = 0.f;
    for (int e = gw; e < E; e += nw) {
        int a = ea[e], b = eb[e];
        float d = 0.f;
        for (int f = lane; f < H2; f += 64)
            d += bf2f(z[(size_t)a * H2 + f]) * bf2f(z[(size_t)b * H2 + f]);
        #pragma unroll
        for (int off = 32; off; off >>= 1) d += __shfl_down(d, off);
        if (lane == 0) {
            float s = 1.f / (1.f + expf(-d));
            float t = (mode == 0) ? -logf(s + 1e-15f) : -logf(1.f - s + 1e-15f);
            sum += t;
        }
    }
    if (lane == 0) wsum[wid] = sum;
    __syncthreads();
    if (threadIdx.x == 0)
        atomicAdd(&loss[mode], wsum[0] + wsum[1] + wsum[2] + wsum[3]);
}

__global__ void k_final(const float* __restrict__ loss,
                        const float* __restrict__ c1, const float* __restrict__ c2,
                        float* __restrict__ out, int N, float invEp, float invEn) {
    if (threadIdx.x == 0 && blockIdx.x == 0) {
        out[N]     = loss[0] * invEp + loss[1] * invEn;
        out[N + 1] = c1[0];
        out[N + 2] = c2[0];
    }
}

// ---------------- launch ----------------

extern "C" void kernel_launch(void* const* d_in, const int* in_sizes, int n_in,
                              void* d_out, int out_size, void* d_ws, size_t ws_size,
                              hipStream_t stream) {
    const float* x   = (const float*)d_in[0];
    const int*   ei  = (const int*)d_in[1];
    const int*   nei = (const int*)d_in[2];
    const float* c1w0 = (const float*)d_in[3];
    const float* c1w1 = (const float*)d_in[4];
    const float* c1b  = (const float*)d_in[5];
    const float* c2w0 = (const float*)d_in[6];
    const float* c2w1 = (const float*)d_in[7];
    const float* c2b  = (const float*)d_in[8];
    const float* c3w0 = (const float*)d_in[9];
    const float* c3w1 = (const float*)d_in[10];
    const float* c3b  = (const float*)d_in[11];
    const float* l1w  = (const float*)d_in[12];
    const float* l1b  = (const float*)d_in[13];
    const float* l2w  = (const float*)d_in[14];
    const float* l2b  = (const float*)d_in[15];
    const float* c1s  = (const float*)d_in[16];
    const float* c2s  = (const float*)d_in[17];

    const int N  = in_sizes[0] / DIN;      // 100000
    const int E  = in_sizes[1] / 2;        // 262144
    const int En = in_sizes[2] / 2;        // 262144

    const int* row = ei;        // src
    const int* col = ei + E;    // dst

    // ---- workspace layout (peak ~134 MB) ----
    char* ws = (char*)d_ws;
    const size_t MB = 1024ull * 1024ull;
    float* wE    = (float*)(ws + 0);                    // E f32 (1MB)
    int*   srcS  = (int*)  (ws + 1 * MB);               // E i32 (1MB)
    float* wS    = (float*)(ws + 2 * MB);               // E f32 (1MB)
    int*   cnt   = (int*)  (ws + 3 * MB);               // N i32
    int*   offs  = (int*)  (ws + 3 * MB + 512 * 1024);  // N i32
    int*   cur   = (int*)  (ws + 4 * MB);               // N i32
    float* dinv  = (float*)(ws + 4 * MB + 512 * 1024);  // N f32
    float* y1    = (float*)(ws + 5 * MB);               // N f32
    float* loss  = (float*)(ws + 5 * MB + 512 * 1024);  // 2 f32
    int*   bsum  = (int*)  (ws + 5 * MB + 516 * 1024);  // 256 i32
    unsigned short* Bt1 = (unsigned short*)(ws + 6 * MB);              // 300*128*2
    unsigned short* Bt2 = (unsigned short*)(ws + 6 * MB + 256 * 1024); // 200*320*2
    unsigned short* Btl = (unsigned short*)(ws + 6 * MB + 512 * 1024); // 256*64*2
    unsigned short* Abf = (unsigned short*)(ws + 8 * MB);   // N*128 bf16 (24.4MiB)
    float* x1    = (float*)(ws + 34 * MB);                  // N*100 f32 (38.1MiB)
    unsigned short* hw1b = (unsigned short*)(ws + 74 * MB); // N*100 bf16 (19.1MiB)
    unsigned short* hC   = (unsigned short*)(ws + 94 * MB); // chunk 50000*320 bf16 (30.5MiB)
    unsigned short* zb   = (unsigned short*)(ws + 94 * MB); // N*100 bf16 (after loop)
    unsigned short* xsb  = (unsigned short*)(ws + 114 * MB);// N*100 bf16

    const int ZG = 1024;
    int gE = (E + 255) / 256;
    int gN = (N + 255) / 256;
    int NB = (N + 1023) / 1024;            // 98 <= 256

    // ---- zero int accumulators ----
    k_zero<<<ZG, 256, 0, stream>>>((float*)cnt, N);
    k_zero<<<ZG, 256, 0, stream>>>((float*)cur, N);
    k_zero<<<1, 256, 0, stream>>>(loss, 2);

    // ---- degree (dst histogram == symmetric src histogram), weights ----
    k_hist<<<gE, 256, 0, stream>>>(col, cnt, E);
    k_dinvI<<<gN, 256, 0, stream>>>(cnt, dinv, N);
    k_w<<<gE, 256, 0, stream>>>(row, col, dinv, wE, E);

    // ---- CSR build: scan + reorder ----
    k_scan1<<<NB, 256, 0, stream>>>(cnt, offs, bsum, N);
    k_scan2<<<1, 256, 0, stream>>>(bsum, NB);
    k_scan3<<<gN, 256, 0, stream>>>(offs, bsum, N);
    k_reorder<<<gE, 256, 0, stream>>>(row, col, wE, offs, cur, srcS, wS, E);

    // ---- weight packs (tiny) ----
    k_packB1<<<(H1 * 128 + 255) / 256, 256, 0, stream>>>(c1w0, c1w1, Bt1);
    k_packB2<<<(200 * 320 + 255) / 256, 256, 0, stream>>>(c2w0, c2w1, Bt2);
    k_packBL<<<(256 * 64 + 255) / 256, 256, 0, stream>>>(l1w, l2w, Btl);

    // ---- conv1 aggregate + bf16 pack: Abf = [x | 0 | t1 | 0] ----
    k_agg1<<<(N + 3) / 4, 256, 0, stream>>>(x, srcS, wS, offs, cnt, Abf, N);

    // ---- conv1 + conv2 MFMA over 2 row chunks ----
    const int RC = 50000;
    for (int r0 = 0; r0 < N; r0 += RC) {
        int rc = (N - r0 < RC) ? (N - r0) : RC;
        dim3 g1((rc + 127) / 128, 3);
        gemm_mfma<<<g1, 256, 0, stream>>>(Abf + (size_t)r0 * 128, 128, Bt1, 128,
                                          c1b, 1, 0, nullptr, hC, rc, 4, H1, 320);
        dim3 g2((rc + 127) / 128, 2);
        gemm_mfma<<<g2, 256, 0, stream>>>(hC, 320, Bt2, 320, nullptr, 0, 1,
                                          x1 + (size_t)r0 * H2, hw1b + (size_t)r0 * H2,
                                          rc, 10, 200, 0);
    }

    // ---- conv2 aggregate (fused bias+relu): x1 = relu(x1 + segsum(w*hw1b) + c2b) ----
    k_agg2<<<(N + 3) / 4, 256, 0, stream>>>(hw1b, srcS, wS, offs, cnt, c2b, x1, N);

    // ---- lin1+lin2 MFMA: xsb/zb = bf16(x1 + relu(x@w + b)) ----
    {
        dim3 g((N + 127) / 128, 2);
        k_linpair<<<g, 256, 0, stream>>>(Abf, Btl, l1b, l2b, x1, xsb, zb, N);
    }

    // ---- conv3: out = xs@w0 + b + segsum(w * (xs@w1)[src]) ----
    k_conv3y<<<(N + 3) / 4, 256, 0, stream>>>(xsb, c3w0, c3w1, c3b, (float*)d_out, y1, N);
    k_agg3<<<gN, 256, 0, stream>>>(y1, srcS, wS, offs, cnt, (float*)d_out, N);

    // ---- losses ----
    k_loss<<<1024, 256, 0, stream>>>(zb, ei, ei + E, E, 0, loss);
    k_loss<<<1024, 256, 0, stream>>>(zb, nei, nei + En, En, 1, loss);
    k_final<<<1, 64, 0, stream>>>(loss, c1s, c2s, (float*)d_out, N, 1.0f / E, 1.0f / En);
}